// Round 1
// baseline (411.895 us; speedup 1.0000x reference)
//
#include <hip/hip_runtime.h>
#include <hip/hip_bf16.h>

#define N_NODES 40000
#define N_EDGES 640000
#define DIM     128

// ---------------------------------------------------------------------------
// GEMM: C[M x 128] = A[M x 128] @ W[128 x 128] (+ bias if addBias)
// Tile: 64 rows x 128 cols per block, BK=32, 256 threads.
// Thread (tidx = t&31 -> 4 cols, tidy = t>>5 -> 8 rows): 8x4 acc.
// ---------------------------------------------------------------------------
__global__ __launch_bounds__(256) void gemm128(const float* __restrict__ A,
                                               const float* __restrict__ W,
                                               const float* __restrict__ bias,
                                               float* __restrict__ C,
                                               int addBias) {
    __shared__ float Bs[32][128];   // [k][n]
    __shared__ float As[32][64];    // [k][m] (transposed)

    const int t    = threadIdx.x;
    const int tidx = t & 31;   // col group: cols 4*tidx .. 4*tidx+3
    const int tidy = t >> 5;   // row group: rows 8*tidy .. 8*tidy+7
    const int rowBase = blockIdx.x * 64;

    float4 acc[8];
#pragma unroll
    for (int j = 0; j < 8; ++j) acc[j] = make_float4(0.f, 0.f, 0.f, 0.f);

    for (int kb = 0; kb < 128; kb += 32) {
        // stage B tile: W[kb..kb+31][0..127]  (1024 float4, 4 per thread)
#pragma unroll
        for (int j = 0; j < 4; ++j) {
            int id = t + 256 * j;
            int r  = id >> 5;        // 0..31
            int c4 = id & 31;        // 0..31
            float4 v = *(const float4*)&W[(kb + r) * 128 + 4 * c4];
            *(float4*)&Bs[r][4 * c4] = v;
        }
        // stage A tile transposed: A[rowBase..+63][kb..kb+31] -> As[k][m]
#pragma unroll
        for (int j = 0; j < 2; ++j) {
            int id = t + 256 * j;    // 0..511
            int r  = id >> 3;        // 0..63
            int k4 = id & 7;         // 0..7
            float4 v = *(const float4*)&A[(size_t)(rowBase + r) * 128 + kb + 4 * k4];
            As[4 * k4 + 0][r] = v.x;
            As[4 * k4 + 1][r] = v.y;
            As[4 * k4 + 2][r] = v.z;
            As[4 * k4 + 3][r] = v.w;
        }
        __syncthreads();
#pragma unroll
        for (int k = 0; k < 32; ++k) {
            float4 b = *(const float4*)&Bs[k][4 * tidx];
#pragma unroll
            for (int j = 0; j < 8; ++j) {
                float a = As[k][8 * tidy + j];
                acc[j].x += a * b.x;
                acc[j].y += a * b.y;
                acc[j].z += a * b.z;
                acc[j].w += a * b.w;
            }
        }
        __syncthreads();
    }

    float4 bv = make_float4(0.f, 0.f, 0.f, 0.f);
    if (addBias) bv = *(const float4*)&bias[4 * tidx];
#pragma unroll
    for (int j = 0; j < 8; ++j) {
        float4 o = acc[j];
        o.x += bv.x; o.y += bv.y; o.z += bv.z; o.w += bv.w;
        *(float4*)&C[(size_t)(rowBase + 8 * tidy + j) * 128 + 4 * tidx] = o;
    }
}

// ---------------------------------------------------------------------------
// CSR build: zero counts -> histogram(row) -> scan -> scatter(col)
// ---------------------------------------------------------------------------
__global__ void zero_kernel(int* __restrict__ p, int n) {
    int i = blockIdx.x * 256 + threadIdx.x;
    if (i < n) p[i] = 0;
}

__global__ void hist_kernel(const int* __restrict__ rows, int* __restrict__ counts) {
    int e = blockIdx.x * 256 + threadIdx.x;
    if (e < N_EDGES) atomicAdd(&counts[rows[e]], 1);
}

// single block, 1024 threads, Hillis-Steele scan over chunks of 1024
__global__ __launch_bounds__(1024) void scan_kernel(const int* __restrict__ counts,
                                                    int* __restrict__ row_ptr,
                                                    int* __restrict__ cursor) {
    __shared__ int sh[1024];
    __shared__ int sbase;
    const int t = threadIdx.x;
    if (t == 0) { sbase = 0; row_ptr[0] = 0; }
    __syncthreads();
    for (int base = 0; base < N_NODES; base += 1024) {
        int i = base + t;
        int c = (i < N_NODES) ? counts[i] : 0;
        int val = c;
        sh[t] = val;
        __syncthreads();
        for (int off = 1; off < 1024; off <<= 1) {
            int a = (t >= off) ? sh[t - off] : 0;
            __syncthreads();
            val += a;
            sh[t] = val;
            __syncthreads();
        }
        int incl = val + sbase;
        if (i < N_NODES) {
            row_ptr[i + 1] = incl;
            cursor[i]      = incl - c;   // exclusive prefix = write cursor
        }
        __syncthreads();
        if (t == 1023) sbase = incl;
        __syncthreads();
    }
}

__global__ void scatter_kernel(const int* __restrict__ rows,
                               const int* __restrict__ cols,
                               int* __restrict__ cursor,
                               int* __restrict__ adj) {
    int e = blockIdx.x * 256 + threadIdx.x;
    if (e < N_EDGES) {
        int r   = rows[e];
        int pos = atomicAdd(&cursor[r], 1);
        adj[pos] = cols[e];
    }
}

// ---------------------------------------------------------------------------
// Aggregation: per node i, acc = sum_{e in CSR(i)} z[adj[e]];
//              h_out[i] = h_in[i] + relu(acc + bias)
// One wave per node (float2 per lane). h_out may alias h_in (own-row only).
// ---------------------------------------------------------------------------
__global__ __launch_bounds__(256) void agg_kernel(const float* __restrict__ z,
                                                  const float* __restrict__ h_in,
                                                  const int* __restrict__ row_ptr,
                                                  const int* __restrict__ adj,
                                                  const float* __restrict__ bias,
                                                  float* __restrict__ h_out) {
    const int wave = threadIdx.x >> 6;               // 0..3
    const int lane = threadIdx.x & 63;
    const int node = blockIdx.x * 4 + wave;
    if (node >= N_NODES) return;

    const int s = row_ptr[node];
    const int e = row_ptr[node + 1];

    float accx = 0.f, accy = 0.f;
    for (int i = s; i < e; ++i) {
        int c = adj[i];
        float2 v = *(const float2*)&z[(size_t)c * DIM + lane * 2];
        accx += v.x;
        accy += v.y;
    }
    float2 b  = *(const float2*)&bias[lane * 2];
    float2 h  = *(const float2*)&h_in[(size_t)node * DIM + lane * 2];
    float rx = accx + b.x; rx = rx > 0.f ? rx : 0.f;
    float ry = accy + b.y; ry = ry > 0.f ? ry : 0.f;
    float2 o = make_float2(h.x + rx, h.y + ry);
    *(float2*)&h_out[(size_t)node * DIM + lane * 2] = o;
}

// ---------------------------------------------------------------------------
extern "C" void kernel_launch(void* const* d_in, const int* in_sizes, int n_in,
                              void* d_out, int out_size, void* d_ws, size_t ws_size,
                              hipStream_t stream) {
    const float* x   = (const float*)d_in[0];
    const int*   ei  = (const int*)d_in[1];      // [2, E]: rows then cols
    const float* W_t = (const float*)d_in[2];
    const float* b_t = (const float*)d_in[3];
    const float* W0  = (const float*)d_in[4];
    const float* b0  = (const float*)d_in[5];
    const float* W1  = (const float*)d_in[6];
    const float* b1  = (const float*)d_in[7];

    const int* rows = ei;
    const int* cols = ei + N_EDGES;

    float* H = (float*)d_out;                    // h lives in d_out (in-place residual)

    // workspace layout
    float* Z       = (float*)d_ws;               // N*D floats
    int*   row_ptr = (int*)(Z + (size_t)N_NODES * DIM);  // N+1
    int*   cursor  = row_ptr + (N_NODES + 1);    // N
    int*   counts  = cursor + N_NODES;           // N
    int*   adj     = counts + N_NODES;           // E

    const int eb = (N_EDGES + 255) / 256;        // 2500
    const int nb = (N_NODES + 255) / 256;        // 157
    const int gemmBlocks = N_NODES / 64;         // 625
    const int aggBlocks  = (N_NODES + 3) / 4;    // 10000

    // CSR build
    zero_kernel<<<nb, 256, 0, stream>>>(counts, N_NODES);
    hist_kernel<<<eb, 256, 0, stream>>>(rows, counts);
    scan_kernel<<<1, 1024, 0, stream>>>(counts, row_ptr, cursor);
    scatter_kernel<<<eb, 256, 0, stream>>>(rows, cols, cursor, adj);

    // h = x @ W_t + b_t
    gemm128<<<gemmBlocks, 256, 0, stream>>>(x, W_t, b_t, H, 1);

    // layer 0: z = h @ W0 ; h += relu(agg + b0)
    gemm128<<<gemmBlocks, 256, 0, stream>>>(H, W0, nullptr, Z, 0);
    agg_kernel<<<aggBlocks, 256, 0, stream>>>(Z, H, row_ptr, adj, b0, H);

    // layer 1: z = h @ W1 ; h += relu(agg + b1)
    gemm128<<<gemmBlocks, 256, 0, stream>>>(H, W1, nullptr, Z, 0);
    agg_kernel<<<aggBlocks, 256, 0, stream>>>(Z, H, row_ptr, adj, b1, H);
}

// Round 2
// 244.586 us; speedup vs baseline: 1.6840x; 1.6840x over previous
//
#include <hip/hip_runtime.h>
#include <hip/hip_bf16.h>

#define N_NODES 40000
#define N_EDGES 640000
#define DIM     128

typedef __attribute__((ext_vector_type(8))) short short8;
typedef __attribute__((ext_vector_type(4))) float f32x4;

__device__ inline short f2bf(float f) {
    __hip_bfloat16 h = __float2bfloat16(f);
    return *reinterpret_cast<short*>(&h);
}
__device__ inline float bf2f(short u) {
    union { unsigned int i; float f; } x;
    x.i = ((unsigned int)(unsigned short)u) << 16;
    return x.f;
}

// ---------------------------------------------------------------------------
// bf16-MFMA GEMM: out[M x 128] = A[M x 128] @ W[128 x 128]
// MODE 0: out fp32 + bias (transform).  MODE 1: out bf16, no bias (layers).
// Block: 64 rows, 4 waves; wave w handles rows wBase..wBase+15, all 128 cols.
// W staged once into LDS in MFMA B-fragment order (conflict-free b128 reads).
// A-fragments loaded directly from global (each element used exactly once).
// ---------------------------------------------------------------------------
template <int MODE>
__global__ __launch_bounds__(256) void mfma_gemm(const float* __restrict__ A,
                                                 const float* __restrict__ W,
                                                 const float* __restrict__ bias,
                                                 float* __restrict__ outF,
                                                 __hip_bfloat16* __restrict__ outB) {
    __shared__ short Ws[128 * 128];   // fragment-order bf16 W, 32 KB

    const int t     = threadIdx.x;
    const int wave  = t >> 6;
    const int l     = t & 63;
    const int nl    = l & 15;         // n within 16-tile / m within row-tile
    const int quad  = l >> 4;
    const int rowBase = blockIdx.x * 64;
    const int wRow  = rowBase + wave * 16;

    // ---- stage W into fragment order ----
    // slot(k,n) = (kb_idx*8 + ntile)*64 + quad*16 + (n&15), 8 ushorts per slot
#pragma unroll
    for (int it = 0; it < 8; ++it) {
        int idx    = t + 256 * it;        // 0..2047
        int n      = idx & 127;
        int kchunk = idx >> 7;            // 0..15, k0 = kchunk*8
        int kb_idx = kchunk >> 2;
        int kq     = kchunk & 3;
        short8 v;
#pragma unroll
        for (int j = 0; j < 8; ++j)
            v[j] = f2bf(W[(kchunk * 8 + j) * 128 + n]);
        int slot = (kb_idx * 8 + (n >> 4)) * 64 + kq * 16 + (n & 15);
        *(short8*)&Ws[slot * 8] = v;
    }
    __syncthreads();

    f32x4 acc[8];
#pragma unroll
    for (int nt = 0; nt < 8; ++nt) acc[nt] = (f32x4){0.f, 0.f, 0.f, 0.f};

#pragma unroll
    for (int kb = 0; kb < 4; ++kb) {
        // A-frag: lane holds A[m = wRow+nl][k = kb*32 + quad*8 + j]
        const float* ap = A + (size_t)(wRow + nl) * 128 + kb * 32 + quad * 8;
        float4 f0 = *(const float4*)ap;
        float4 f1 = *(const float4*)(ap + 4);
        short8 afrag;
        afrag[0] = f2bf(f0.x); afrag[1] = f2bf(f0.y);
        afrag[2] = f2bf(f0.z); afrag[3] = f2bf(f0.w);
        afrag[4] = f2bf(f1.x); afrag[5] = f2bf(f1.y);
        afrag[6] = f2bf(f1.z); afrag[7] = f2bf(f1.w);
#pragma unroll
        for (int nt = 0; nt < 8; ++nt) {
            short8 bfrag = *(const short8*)&Ws[((kb * 8 + nt) * 64 + l) * 8];
            acc[nt] = __builtin_amdgcn_mfma_f32_16x16x32_bf16(afrag, bfrag, acc[nt], 0, 0, 0);
        }
    }

    // ---- epilogue: C/D layout col = l&15, row = quad*4 + reg ----
#pragma unroll
    for (int nt = 0; nt < 8; ++nt) {
        int col = nt * 16 + nl;
        float bv = (MODE == 0) ? bias[col] : 0.f;
#pragma unroll
        for (int r = 0; r < 4; ++r) {
            int row = quad * 4 + r;
            float v = acc[nt][r] + bv;
            if (MODE == 0)
                outF[(size_t)(wRow + row) * 128 + col] = v;
            else
                *(short*)&outB[(size_t)(wRow + row) * 128 + col] = f2bf(v);
        }
    }
}

// ---------------------------------------------------------------------------
// CSR build
// ---------------------------------------------------------------------------
__global__ void hist_kernel(const int* __restrict__ rows, int* __restrict__ counts) {
    int e = blockIdx.x * 256 + threadIdx.x;
    if (e < N_EDGES) atomicAdd(&counts[rows[e]], 1);
}

__global__ __launch_bounds__(256) void scan_local(const int* __restrict__ counts,
                                                  int* __restrict__ excl,
                                                  int* __restrict__ blkTot) {
    __shared__ int sh[256];
    const int t = threadIdx.x;
    int i = blockIdx.x * 256 + t;
    int c = (i < N_NODES) ? counts[i] : 0;
    int val = c;
    sh[t] = val;
    __syncthreads();
    for (int off = 1; off < 256; off <<= 1) {
        int a = (t >= off) ? sh[t - off] : 0;
        __syncthreads();
        val += a;
        sh[t] = val;
        __syncthreads();
    }
    if (i < N_NODES) excl[i] = val - c;
    if (t == 255) blkTot[blockIdx.x] = val;
}

__global__ __launch_bounds__(256) void scan_blk(const int* __restrict__ blkTot,
                                                int* __restrict__ blkOff,
                                                int nblk) {
    __shared__ int sh[256];
    const int t = threadIdx.x;
    int c = (t < nblk) ? blkTot[t] : 0;
    int val = c;
    sh[t] = val;
    __syncthreads();
    for (int off = 1; off < 256; off <<= 1) {
        int a = (t >= off) ? sh[t - off] : 0;
        __syncthreads();
        val += a;
        sh[t] = val;
        __syncthreads();
    }
    if (t < nblk) blkOff[t] = val - c;
}

__global__ __launch_bounds__(256) void scan_final(const int* __restrict__ excl,
                                                  const int* __restrict__ blkOff,
                                                  int* __restrict__ cursor,
                                                  int* __restrict__ row_ptr) {
    int i = blockIdx.x * 256 + threadIdx.x;
    if (i < N_NODES) {
        int v = excl[i] + blkOff[blockIdx.x];
        cursor[i]  = v;
        row_ptr[i] = v;
    }
    if (i == 0) row_ptr[N_NODES] = N_EDGES;
}

__global__ void scatter_kernel(const int* __restrict__ rows,
                               const int* __restrict__ cols,
                               int* __restrict__ cursor,
                               int* __restrict__ adj) {
    int e = blockIdx.x * 256 + threadIdx.x;
    if (e < N_EDGES) {
        int r   = rows[e];
        int pos = atomicAdd(&cursor[r], 1);
        adj[pos] = cols[e];
    }
}

// ---------------------------------------------------------------------------
// Aggregation (bf16 z): one wave per node.
// quad = l>>4 selects one of 4 edges per iteration; sl = l&15 selects a
// 16 B (8 bf16) chunk of the 256 B row. fp32 accumulate, cross-quad
// shfl_xor reduce, then quad 0 writes h += relu(acc + b) as 2x float4.
// ---------------------------------------------------------------------------
__global__ __launch_bounds__(256) void agg_kernel(const __hip_bfloat16* __restrict__ z,
                                                  const int* __restrict__ row_ptr,
                                                  const int* __restrict__ adj,
                                                  const float* __restrict__ bias,
                                                  float* __restrict__ h) {
    const int wave = threadIdx.x >> 6;
    const int l    = threadIdx.x & 63;
    const int quad = l >> 4;
    const int sl   = l & 15;
    const int node = blockIdx.x * 4 + wave;
    if (node >= N_NODES) return;

    const int s = row_ptr[node];
    const int e = row_ptr[node + 1];

    float acc[8];
#pragma unroll
    for (int j = 0; j < 8; ++j) acc[j] = 0.f;

    for (int it = s + quad; it < e; it += 4) {
        int c = adj[it];
        short8 v = *(const short8*)&z[(size_t)c * DIM + sl * 8];
#pragma unroll
        for (int j = 0; j < 8; ++j) acc[j] += bf2f(v[j]);
    }

#pragma unroll
    for (int j = 0; j < 8; ++j) acc[j] += __shfl_xor(acc[j], 16, 64);
#pragma unroll
    for (int j = 0; j < 8; ++j) acc[j] += __shfl_xor(acc[j], 32, 64);

    if (quad == 0) {
        float* hp = h + (size_t)node * DIM + sl * 8;
        float4 h0 = *(float4*)hp;
        float4 h1 = *(float4*)(hp + 4);
        float4 b0 = *(const float4*)&bias[sl * 8];
        float4 b1 = *(const float4*)&bias[sl * 8 + 4];
        float r0 = acc[0] + b0.x, r1 = acc[1] + b0.y, r2 = acc[2] + b0.z, r3 = acc[3] + b0.w;
        float r4 = acc[4] + b1.x, r5 = acc[5] + b1.y, r6 = acc[6] + b1.z, r7 = acc[7] + b1.w;
        h0.x += r0 > 0.f ? r0 : 0.f;  h0.y += r1 > 0.f ? r1 : 0.f;
        h0.z += r2 > 0.f ? r2 : 0.f;  h0.w += r3 > 0.f ? r3 : 0.f;
        h1.x += r4 > 0.f ? r4 : 0.f;  h1.y += r5 > 0.f ? r5 : 0.f;
        h1.z += r6 > 0.f ? r6 : 0.f;  h1.w += r7 > 0.f ? r7 : 0.f;
        *(float4*)hp       = h0;
        *(float4*)(hp + 4) = h1;
    }
}

// ---------------------------------------------------------------------------
extern "C" void kernel_launch(void* const* d_in, const int* in_sizes, int n_in,
                              void* d_out, int out_size, void* d_ws, size_t ws_size,
                              hipStream_t stream) {
    const float* x   = (const float*)d_in[0];
    const int*   ei  = (const int*)d_in[1];
    const float* W_t = (const float*)d_in[2];
    const float* b_t = (const float*)d_in[3];
    const float* W0  = (const float*)d_in[4];
    const float* b0  = (const float*)d_in[5];
    const float* W1  = (const float*)d_in[6];
    const float* b1  = (const float*)d_in[7];

    const int* rows = ei;
    const int* cols = ei + N_EDGES;

    float* H = (float*)d_out;

    // workspace layout
    __hip_bfloat16* Z = (__hip_bfloat16*)d_ws;                 // N*D bf16
    int* row_ptr = (int*)((char*)d_ws + (size_t)N_NODES * DIM * 2);
    int* cursor  = row_ptr + (N_NODES + 1);
    int* counts  = cursor + N_NODES;
    int* excl    = counts + N_NODES;
    int* adj     = excl + N_NODES;                              // E ints
    int* blkTot  = adj + N_EDGES;
    int* blkOff  = blkTot + 256;

    const int eb = (N_EDGES + 255) / 256;   // 2500
    const int nb = (N_NODES + 255) / 256;   // 157
    const int gemmBlocks = N_NODES / 64;    // 625
    const int aggBlocks  = (N_NODES + 3) / 4;

    // CSR build
    hipMemsetAsync(counts, 0, N_NODES * sizeof(int), stream);
    hist_kernel<<<eb, 256, 0, stream>>>(rows, counts);
    scan_local<<<nb, 256, 0, stream>>>(counts, excl, blkTot);
    scan_blk<<<1, 256, 0, stream>>>(blkTot, blkOff, nb);
    scan_final<<<nb, 256, 0, stream>>>(excl, blkOff, cursor, row_ptr);
    scatter_kernel<<<eb, 256, 0, stream>>>(rows, cols, cursor, adj);

    // h = x @ W_t + b_t  (fp32 out)
    mfma_gemm<0><<<gemmBlocks, 256, 0, stream>>>(x, W_t, b_t, H, nullptr);

    // layer 0
    mfma_gemm<1><<<gemmBlocks, 256, 0, stream>>>(H, W0, nullptr, nullptr, Z);
    agg_kernel<<<aggBlocks, 256, 0, stream>>>(Z, row_ptr, adj, b0, H);

    // layer 1
    mfma_gemm<1><<<gemmBlocks, 256, 0, stream>>>(H, W1, nullptr, nullptr, Z);
    agg_kernel<<<aggBlocks, 256, 0, stream>>>(Z, row_ptr, adj, b1, H);
}